// Round 11
// baseline (103.530 us; speedup 1.0000x reference)
//
#include <hip/hip_runtime.h>

#define M_PAD 512

typedef float f32x4 __attribute__((ext_vector_type(4)));
typedef int   i32x4 __attribute__((ext_vector_type(4)));

// Pass 1: run-boundary detection over sorted ri, int4-vectorized (4 samples
// per thread), WITH gap-ray zeroing (absent rays get start=endx=0) so no
// d_ws memset dispatch. T % 4 == 0 (T = 4194304).
__global__ void boundary_kernel(const int* __restrict__ ri,
                                int* __restrict__ start, int* __restrict__ endx,
                                int N, int T) {
    int t = blockIdx.x * blockDim.x + threadIdx.x;
    int base = t * 4;
    if (base >= T) return;
    i32x4 v = __builtin_nontemporal_load(reinterpret_cast<const i32x4*>(ri) + t);
    int prev = (base == 0) ? -1 : ri[base - 1];   // scalar re-read, L1/L2 hit

    #pragma unroll
    for (int e = 0; e < 4; ++e) {
        int r  = v[e];
        int rp = (e == 0) ? prev : v[e - 1];
        if (rp != r) {
            start[r] = base + e;
            if (rp >= 0) endx[rp] = base + e;
            for (int g = rp + 1; g < r; ++g) { start[g] = 0; endx[g] = 0; }
        }
    }
    if (base + 4 >= T) {   // last vector: close final run + zero trailing gap
        endx[v[3]] = T;
        for (int g = v[3] + 1; g < N; ++g) { start[g] = 0; endx[g] = 0; }
    }
}

// Pass 2 (fused, grid-stride, one slot per iteration, lane-dense access).
// All output stores nontemporal (write-once, never re-read); ts/te loads
// nontemporal too (read-once) to keep L2 free for the store path.
__global__ __launch_bounds__(256)
void fused_kernel(const float* __restrict__ rays,
                  const float* __restrict__ ts,
                  const float* __restrict__ te,
                  const int* __restrict__ start,
                  const int* __restrict__ endx,
                  float* __restrict__ xyz_out,     // (T,4)
                  float* __restrict__ ray_valid,   // (N,512)
                  float* __restrict__ z_vals,      // (N,512)
                  float* __restrict__ dists,       // (N,512)
                  float* __restrict__ xyz_w,       // (N,512,4)
                  float* __restrict__ whole_valid, // (N,)
                  int total) {
    const int gsize = gridDim.x * blockDim.x;
    for (int idx = blockIdx.x * blockDim.x + threadIdx.x; idx < total; idx += gsize) {
        int r = idx >> 9;            // 512 slots per ray; wave-uniform r
        int j = idx & (M_PAD - 1);
        int s = start[r];
        int cnt = endx[r] - s;

        float z = 0.0f, dd = 0.0f, v = 0.0f;
        f32x4 pt = {0.f, 0.f, 0.f, 0.f};

        if (j < cnt) {
            int i = s + j;
            float a = __builtin_nontemporal_load(&ts[i]);
            float b = __builtin_nontemporal_load(&te[i]);
            z  = (a + b) * 0.5f;
            dd = b - a;
            v  = 1.0f;
            const float* rc = rays + (size_t)r * 6;   // wave-uniform -> L1 broadcast
            pt.x = fmaf(z, rc[3], rc[0]);
            pt.y = fmaf(z, rc[4], rc[1]);
            pt.z = fmaf(z, rc[5], rc[2]);
            __builtin_nontemporal_store(pt, reinterpret_cast<f32x4*>(xyz_out) + i);
        }

        __builtin_nontemporal_store(z,  &z_vals[idx]);
        __builtin_nontemporal_store(dd, &dists[idx]);
        __builtin_nontemporal_store(v,  &ray_valid[idx]);
        __builtin_nontemporal_store(pt, reinterpret_cast<f32x4*>(xyz_w) + idx);

        if (j == 0) whole_valid[r] = 1.0f;
    }
}

extern "C" void kernel_launch(void* const* d_in, const int* in_sizes, int n_in,
                              void* d_out, int out_size, void* d_ws, size_t ws_size,
                              hipStream_t stream) {
    const float* rays = (const float*)d_in[0];  // (N,6)
    const int*   ri   = (const int*)d_in[1];    // (T,) sorted
    const float* ts   = (const float*)d_in[2];  // (T,)
    const float* te   = (const float*)d_in[3];  // (T,)
    const int N = in_sizes[0] / 6;
    const int T = in_sizes[1];

    float* out         = (float*)d_out;
    float* xyz_out     = out;                                    // T*4
    float* ray_valid   = xyz_out + (size_t)T * 4;                // N*512
    float* z_vals      = ray_valid + (size_t)N * M_PAD;          // N*512
    float* dists       = z_vals + (size_t)N * M_PAD;             // N*512
    float* whole_valid = dists + (size_t)N * M_PAD;              // N
    float* xyz_w       = whole_valid + N;                        // N*512*4

    int* start = (int*)d_ws;
    int* endx  = start + N;

    const int B = 256;
    const int Tq = T / 4;
    boundary_kernel<<<(Tq + B - 1) / B, B, 0, stream>>>(ri, start, endx, N, T);
    const int total = N * M_PAD;
    fused_kernel<<<2048, B, 0, stream>>>(rays, ts, te, start, endx,
                                         xyz_out, ray_valid, z_vals,
                                         dists, xyz_w, whole_valid,
                                         total);
}

// Round 12
// 68.944 us; speedup vs baseline: 1.5017x; 1.5017x over previous
//
#include <hip/hip_runtime.h>

#define M_PAD 512

typedef float f32x4 __attribute__((ext_vector_type(4)));

// Wave-parallel lower_bound over sorted ri[0..Tn): first idx with ri[idx] >= target.
// 65-ary partition per round: 64 lanes probe interior points, ballot gives the
// bracket. len shrinks ~65x/round: 4.19M -> 64K -> 1K -> 16 -> linear finish.
// All arithmetic fits int32 (len*(l+1) <= 4.19M*64 < 2^31).
__device__ __forceinline__ int lower_bound_wave(const int* __restrict__ ri,
                                                int Tn, int target, int lane) {
    int lo = 0, hi = Tn;
    while (hi - lo > 64) {
        int len = hi - lo;
        int probe = lo + (len * (lane + 1)) / 65;       // strictly inside (lo,hi)
        int v = ri[probe];
        unsigned long long m = __ballot(v < target);     // prefix mask (sorted)
        int k = __popcll(m);
        int nlo = (k == 0)  ? lo : lo + (len * k) / 65;
        int nhi = (k == 64) ? hi : lo + (len * (k + 1)) / 65;
        lo = nlo; hi = nhi;
    }
    int p = lo + lane;
    int v = (p < hi) ? ri[p] : 2147483647;               // sentinel >= any target
    unsigned long long m = __ballot(v < target);
    return lo + __popcll(m);
}

// Single-dispatch fused kernel. Block b covers half a ray:
//   r = b>>1, slots j in [ (b&1)*256, (b&1)*256+256 ).
// Waves 0/1 binary-search start=lb(r), end=lb(r+1); then the R10-proven body:
// one slot per thread, dense lane-consecutive loads (i = s+j) and nt stores
// (write-once outputs bypass L2 allocation). No d_ws, no boundary pass.
__global__ __launch_bounds__(256)
void mono_kernel(const float* __restrict__ rays,
                 const int* __restrict__ ri,
                 const float* __restrict__ ts,
                 const float* __restrict__ te,
                 float* __restrict__ xyz_out,     // (T,4)
                 float* __restrict__ ray_valid,   // (N,512)
                 float* __restrict__ z_vals,      // (N,512)
                 float* __restrict__ dists,       // (N,512)
                 float* __restrict__ xyz_w,       // (N,512,4)
                 float* __restrict__ whole_valid, // (N,)
                 int T) {
    const int b = blockIdx.x;
    const int r = b >> 1;
    const int h = b & 1;
    const int tid = threadIdx.x;
    const int wave = tid >> 6, lane = tid & 63;

    __shared__ int sh[2];
    if (wave < 2) {
        int lb = lower_bound_wave(ri, T, r + wave, lane);
        if (lane == 0) sh[wave] = lb;
    }
    __syncthreads();
    const int s = sh[0];
    const int cnt = sh[1] - s;

    const int j = h * 256 + tid;
    const int idx = (r << 9) + j;

    float z = 0.0f, dd = 0.0f, v = 0.0f;
    f32x4 pt = {0.f, 0.f, 0.f, 0.f};

    if (j < cnt) {
        int i = s + j;
        float a = ts[i], bb = te[i];          // dense: lane-consecutive i
        z  = (a + bb) * 0.5f;
        dd = bb - a;
        v  = 1.0f;
        const float* rc = rays + (size_t)r * 6;   // wave-uniform -> broadcast
        pt.x = fmaf(z, rc[3], rc[0]);
        pt.y = fmaf(z, rc[4], rc[1]);
        pt.z = fmaf(z, rc[5], rc[2]);
        __builtin_nontemporal_store(pt, reinterpret_cast<f32x4*>(xyz_out) + i);
    }

    __builtin_nontemporal_store(z,  &z_vals[idx]);
    __builtin_nontemporal_store(dd, &dists[idx]);
    __builtin_nontemporal_store(v,  &ray_valid[idx]);
    __builtin_nontemporal_store(pt, reinterpret_cast<f32x4*>(xyz_w) + idx);

    if (j == 0) whole_valid[r] = 1.0f;
}

extern "C" void kernel_launch(void* const* d_in, const int* in_sizes, int n_in,
                              void* d_out, int out_size, void* d_ws, size_t ws_size,
                              hipStream_t stream) {
    const float* rays = (const float*)d_in[0];  // (N,6)
    const int*   ri   = (const int*)d_in[1];    // (T,) sorted
    const float* ts   = (const float*)d_in[2];  // (T,)
    const float* te   = (const float*)d_in[3];  // (T,)
    const int N = in_sizes[0] / 6;
    const int T = in_sizes[1];

    float* out         = (float*)d_out;
    float* xyz_out     = out;                                    // T*4
    float* ray_valid   = xyz_out + (size_t)T * 4;                // N*512
    float* z_vals      = ray_valid + (size_t)N * M_PAD;          // N*512
    float* dists       = z_vals + (size_t)N * M_PAD;             // N*512
    float* whole_valid = dists + (size_t)N * M_PAD;              // N
    float* xyz_w       = whole_valid + N;                        // N*512*4

    mono_kernel<<<N * 2, 256, 0, stream>>>(rays, ri, ts, te,
                                           xyz_out, ray_valid, z_vals,
                                           dists, xyz_w, whole_valid, T);
}